// Round 11
// baseline (311.064 us; speedup 1.0000x reference)
//
#include <hip/hip_runtime.h>
#include <math.h>
#include <cstdint>
#include <cstddef>

// ---------------------------------------------------------------------------
// Transformer-XL relative multihead attention, MI355X (gfx950)
// S=1024, M=1024, T=2048, B=4, D=1024, H=16, DH=64
// R19: dead-work elimination in the qkv GEMM. attn reads Q only for t>=1024
//      (rows b*2048+1024..), so the Q-segment computes only those m-tiles:
//      QK blocks 256->192 (K-cols 128 + Q-cols 64), total 416->352 blocks
//      (-15.4% qkv work, -8.6 GF, -8MB writes). 352%8==0 keeps bijective
//      XCD swizzle. Uncomputed Q region is never read (proj overwrites it
//      later). Everything else identical to R18 (309.1us; attn 89.4 proven).
// ---------------------------------------------------------------------------

typedef _Float16 half_t;
typedef _Float16 half8 __attribute__((ext_vector_type(8)));
typedef _Float16 half4v __attribute__((ext_vector_type(4)));
typedef float f32x4 __attribute__((ext_vector_type(4)));

#define S_LEN 1024
#define M_LEN 1024
#define T_LEN 2048
#define BATCH 4
#define NHEAD 16

__device__ inline void async_copy16(const half_t* g, half_t* l) {
  __builtin_amdgcn_global_load_lds(
      (const __attribute__((address_space(1))) void*)g,
      (__attribute__((address_space(3))) void*)l, 16, 0, 0);
}

// ---- fused pre-pass: convert (b-major cbf | posb) + weight transposes -----
__global__ __launch_bounds__(256) void k_pre(const float* __restrict__ mem,
                                             const float* __restrict__ x,
                                             const float* __restrict__ pos,
                                             const float* __restrict__ Wqkv,
                                             const float* __restrict__ Wrel,
                                             const float* __restrict__ Wo,
                                             half_t* __restrict__ cbf,
                                             half_t* __restrict__ posb,
                                             half_t* __restrict__ wqkvT,
                                             half_t* __restrict__ wrelT,
                                             half_t* __restrict__ woT) {
  __shared__ float tile[64][65];
  const int bid = blockIdx.x;
  const int t = threadIdx.x;
  if (bid < 10240) {
    const int i = bid * 256 + t;  // 2621440 float4s total
    if (i < 2097152) {            // mem (sel=0) | x (sel=1), b-major dest
      const int off = i & 1048575;
      const int sel = i >> 20;
      const float4 v = ((const float4*)(sel ? x : mem))[off];
      const int row = off >> 8, d4 = off & 255;        // src row = t*4+b
      const int drow = (row & 3) * 2048 + sel * 1024 + (row >> 2);
      half4v h;
      h[0] = (half_t)v.x; h[1] = (half_t)v.y; h[2] = (half_t)v.z; h[3] = (half_t)v.w;
      ((half4v*)cbf)[(drow << 8) + d4] = h;
    } else {                      // pos, linear
      const int off = i - 2097152;
      const float4 v = ((const float4*)pos)[off];
      half4v h;
      h[0] = (half_t)v.x; h[1] = (half_t)v.y; h[2] = (half_t)v.z; h[3] = (half_t)v.w;
      ((half4v*)posb)[off] = h;
    }
    return;
  }
  const int tb = bid - 10240;
  const int bx = tb & 15, y = tb >> 4;
  const float* src; half_t* dst; int C, c0;
  if (y < 48)      { src = Wqkv; dst = wqkvT; C = 3072; c0 = y * 64; }
  else if (y < 64) { src = Wrel; dst = wrelT; C = 1024; c0 = (y - 48) * 64; }
  else             { src = Wo;   dst = woT;   C = 1024; c0 = (y - 64) * 64; }
  const int r0 = bx * 64;
  const int tx = t & 63, ty4 = t >> 6;
#pragma unroll
  for (int k = 0; k < 16; ++k) {
    int row = k * 4 + ty4;
    tile[row][tx] = src[(size_t)(r0 + row) * C + c0 + tx];
  }
  __syncthreads();
#pragma unroll
  for (int k = 0; k < 16; ++k) {
    int orow = k * 4 + ty4;
    dst[(size_t)(c0 + orow) * 1024 + r0 + tx] = (half_t)tile[tx][orow];
  }
}

// ---------- 256^2-tile 8-phase counted-vmcnt GEMM: k | q(live) | vT | pos ---
// 512 threads = 8 waves (2M x 4N); per-wave C = 128x64 (8x4 fragments).
// Schedule identical to R18 (race-checked, verified): per K-tile 4 phases =
// 4 C-quadrants x 16 MFMA; per phase stage one half-tile of a future tile;
// one vmcnt(2)+barrier gate per K-tile. Q-segment computes only t>=1024 rows.
#define QK_STA(tile_, h_)                                                      \
  do {                                                                         \
    _Pragma("unroll") for (int i_ = 0; i_ < 2; ++i_) {                         \
      const int r_ = (t >> 3) + i_ * 64;                                       \
      async_copy16(&A[(size_t)(m0 + (h_) * 128 + r_) * 1024 +                  \
                      (tile_) * 64 + scl],                                     \
                   &sA[(tile_) & 1][h_][r_][(t & 7) * 8]);                     \
    }                                                                          \
  } while (0)

#define QK_STB(tile_, h_)                                                      \
  do {                                                                         \
    _Pragma("unroll") for (int i_ = 0; i_ < 2; ++i_) {                         \
      const int r_ = (t >> 3) + i_ * 64;                                       \
      async_copy16(&B[(size_t)(n0 + (h_) * 128 + r_) * 1024 +                  \
                      (tile_) * 64 + scl],                                     \
                   &sB[(tile_) & 1][h_][r_][(t & 7) * 8]);                     \
    }                                                                          \
  } while (0)

#define QK_LDA(d_, mq_)                                                        \
  do {                                                                         \
    _Pragma("unroll") for (int mt_ = 0; mt_ < 4; ++mt_)                        \
      _Pragma("unroll") for (int ks_ = 0; ks_ < 2; ++ks_) {                    \
        const int lr_ = ((mq_) * 4 + mt_) * 16 + l15;                          \
        af[mt_][ks_] = *(const half8*)&sA[d_][wha][lr_]                        \
                           [((ks_ * 4 + quad) ^ (lr_ & 7)) * 8];               \
      }                                                                        \
  } while (0)

#define QK_LDB(d_, nh_)                                                        \
  do {                                                                         \
    _Pragma("unroll") for (int ntl_ = 0; ntl_ < 2; ++ntl_)                     \
      _Pragma("unroll") for (int ks_ = 0; ks_ < 2; ++ks_) {                    \
        const int lr_ = wnl + ((nh_) * 2 + ntl_) * 16 + l15;                   \
        bf[nh_][ntl_][ks_] = *(const half8*)&sB[d_][whb][lr_]                  \
                                 [((ks_ * 4 + quad) ^ (lr_ & 7)) * 8];         \
      }                                                                        \
  } while (0)

#define QK_MMA(mq_, nh_)                                                       \
  do {                                                                         \
    __builtin_amdgcn_s_setprio(1);                                             \
    _Pragma("unroll") for (int mt_ = 0; mt_ < 4; ++mt_)                        \
      _Pragma("unroll") for (int ntl_ = 0; ntl_ < 2; ++ntl_)                   \
        _Pragma("unroll") for (int ks_ = 0; ks_ < 2; ++ks_)                    \
          acc[(mq_) * 4 + mt_][(nh_) * 2 + ntl_] =                             \
              __builtin_amdgcn_mfma_f32_16x16x32_f16(                          \
                  af[mt_][ks_], bf[nh_][ntl_][ks_],                            \
                  acc[(mq_) * 4 + mt_][(nh_) * 2 + ntl_], 0, 0, 0);            \
    __builtin_amdgcn_s_setprio(0);                                             \
  } while (0)

__global__ __launch_bounds__(512, 2) void k_gemm_qkv_pos(const half_t* __restrict__ cbf,
                                                         const half_t* __restrict__ wqkvT,
                                                         half_t* __restrict__ qkv,
                                                         const half_t* __restrict__ posb,
                                                         const half_t* __restrict__ wrelT,
                                                         half_t* __restrict__ rb,
                                                         half_t* __restrict__ vT) {
  __shared__ half_t sA[2][2][128][64];   // 64 KB
  __shared__ half_t sB[2][2][128][64];   // 64 KB
  const int t = threadIdx.x;
  const int wave = t >> 6, lane = t & 63, quad = lane >> 4, l15 = lane & 15;
  // bijective XCD swizzle (352 % 8 == 0): each XCD gets a contiguous chunk
  const int bid0 = blockIdx.x;
  const int bid = (bid0 & 7) * 44 + (bid0 >> 3);
  const half_t* A; const half_t* B; half_t* C; int m0, n0, N;
  if (bid < 128) {        // K: cbf[8192] @ Wk^T -> qkv cols [1024,2048)
    A = cbf;  B = wqkvT; C = qkv; N = 2048;
    m0 = (bid & 31) * 256; n0 = 1024 + (bid >> 5) * 256;
  } else if (bid < 192) { // Q: only rows t>=1024 per batch (attn-live)
    const int q = bid - 128;
    const int ml = q & 15;          // batch = ml>>2, local t-tile = ml&3
    A = cbf;  B = wqkvT; C = qkv; N = 2048;
    m0 = (ml >> 2) * 2048 + 1024 + (ml & 3) * 256;
    n0 = (q >> 4) * 256;
  } else if (bid < 320) { // V^T: Wv^T[1024] @ cbf^T -> vT[1024][8192]
    const int b2 = bid - 192;
    A = wqkvT + 2048 * 1024; B = cbf; C = vT; N = 8192;
    m0 = (b2 & 3) * 256; n0 = (b2 >> 2) * 256;
  } else {                // pos: posb[2048] @ Wrel^T -> rb[2048][1024]
    const int b2 = bid - 320;
    A = posb; B = wrelT; C = rb; N = 1024;
    m0 = (b2 & 7) * 256; n0 = (b2 >> 3) * 256;
  }
  // staging geometry: 512 threads cover 64 rows x 8 chunks per copy round;
  // XOR pre-swizzled global source chunk, linear LDS dest (rule #21).
  const int scl = ((t & 7) ^ ((t >> 3) & 7)) * 8;
  // fragment geometry
  const int wm = (wave >> 2) * 128, wn = (wave & 3) * 64;
  const int wha = wave >> 2;            // wave's static A-half
  const int whb = (wave & 3) >> 1;      // wave's static B-half
  const int wnl = (wave & 1) * 64;      // local B row base within half

  f32x4 acc[8][4] = {};
  half8 af[4][2], bf[2][2][2];

  // prologue: tile 0 fully + (1).A0 -> exactly 1 half-tile in flight at gate
  QK_STA(0, 0); QK_STA(0, 1); QK_STB(0, 0); QK_STB(0, 1); QK_STA(1, 0);

  for (int kt = 0; kt < 16; ++kt) {
    const int d = kt & 1;
    asm volatile("s_waitcnt vmcnt(2)" ::: "memory");   // counted gate, not 0
    __builtin_amdgcn_s_barrier();
    // ph1: quadrant (m0..3, n0..1)
    QK_LDA(d, 0); QK_LDB(d, 0); QK_STA(kt + 1, 1);
    __builtin_amdgcn_s_barrier();
    QK_MMA(0, 0);
    __builtin_amdgcn_s_barrier();
    // ph2: quadrant (m0..3, n2..3)
    QK_LDB(d, 1); QK_STB(kt + 1, 0);
    __builtin_amdgcn_s_barrier();
    QK_MMA(0, 1);
    __builtin_amdgcn_s_barrier();
    // ph3: quadrant (m4..7, n0..1)
    QK_LDA(d, 1); QK_STB(kt + 1, 1);
    __builtin_amdgcn_s_barrier();
    QK_MMA(1, 0);
    __builtin_amdgcn_s_barrier();
    // ph4: quadrant (m4..7, n2..3)
    QK_STA(kt + 2, 0);
    __builtin_amdgcn_s_barrier();
    QK_MMA(1, 1);
    // next iteration's gate barrier closes this tile
  }

#pragma unroll
  for (int mt = 0; mt < 8; ++mt)
#pragma unroll
    for (int nt = 0; nt < 4; ++nt)
#pragma unroll
      for (int r = 0; r < 4; ++r)
        C[(size_t)(m0 + wm + mt * 16 + quad * 4 + r) * N + n0 + wn + nt * 16 + l15] =
            (half_t)acc[mt][nt][r];
}

// ------- proj GEMM: 128x256 tiles, 8-wave dbuf 2-phase, split-K=2 ----------
#define PJ_STAGE(buf_, k0_)                                                    \
  do {                                                                         \
    _Pragma("unroll") for (int i_ = 0; i_ < 2; ++i_) {                         \
      const int r0_ = wave * 16 + i_ * 8;                                      \
      async_copy16(&A[(size_t)(m0 + r0_ + srw) * 1024 + (k0_) + scl],          \
                   &pA[buf_][r0_][0]);                                         \
    }                                                                          \
    _Pragma("unroll") for (int i_ = 0; i_ < 4; ++i_) {                         \
      const int r0_ = wave * 32 + i_ * 8;                                      \
      async_copy16(&B[(size_t)(n0 + r0_ + srw) * 1024 + (k0_) + scl],          \
                   &pB[buf_][r0_][0]);                                         \
    }                                                                          \
  } while (0)

#define PJ_COMPUTE(d_)                                                         \
  do {                                                                         \
    _Pragma("unroll") for (int ks_ = 0; ks_ < 2; ++ks_) {                      \
      half8 bf_[4];                                                            \
      _Pragma("unroll") for (int nt_ = 0; nt_ < 4; ++nt_) {                    \
        const int rw_ = wn + nt_ * 16 + l15;                                   \
        bf_[nt_] =                                                             \
            *(const half8*)&pB[d_][rw_][((ks_ * 4 + quad) ^ (rw_ & 7)) * 8];   \
      }                                                                        \
      half8 af_[4];                                                            \
      _Pragma("unroll") for (int mt_ = 0; mt_ < 4; ++mt_) {                    \
        const int rw_ = wm + mt_ * 16 + l15;                                   \
        af_[mt_] =                                                             \
            *(const half8*)&pA[d_][rw_][((ks_ * 4 + quad) ^ (rw_ & 7)) * 8];   \
      }                                                                        \
      __builtin_amdgcn_s_setprio(1);                                           \
      _Pragma("unroll") for (int mt_ = 0; mt_ < 4; ++mt_)                      \
        _Pragma("unroll") for (int nt_ = 0; nt_ < 4; ++nt_)                    \
          acc[mt_][nt_] = __builtin_amdgcn_mfma_f32_16x16x32_f16(              \
              af_[mt_], bf_[nt_], acc[mt_][nt_], 0, 0, 0);                     \
      __builtin_amdgcn_s_setprio(0);                                           \
    }                                                                          \
  } while (0)

__global__ __launch_bounds__(512, 2) void k_gemm_proj(const half_t* __restrict__ av,
                                                      const half_t* __restrict__ woT,
                                                      half_t* __restrict__ out0,
                                                      half_t* __restrict__ out1) {
  __shared__ half_t pA[2][128][64];     // 32 KB
  __shared__ half_t pB[2][256][64];     // 64 KB
  const int t = threadIdx.x;
  const int wave = t >> 6, lane = t & 63, quad = lane >> 4, l15 = lane & 15;
  const int bid0 = blockIdx.x;
  const int bs = (bid0 & 7) * 32 + (bid0 >> 3);
  const int h = bs >> 7, b2 = bs & 127;
  const int m0 = (b2 & 31) * 128, n0 = (b2 >> 5) * 256;
  const half_t* A = av + h * 512;
  const half_t* B = woT + h * 512;
  half_t* C = h ? out1 : out0;
  const int srw = lane >> 3;
  const int scl = ((lane & 7) ^ srw) * 8;
  const int wm = (wave >> 2) * 64, wn = (wave & 3) * 64;

  f32x4 acc[4][4] = {};

  PJ_STAGE(0, 0);
  __syncthreads();
  int d = 0;
  for (int kt = 0; kt < 7; ++kt) {      // K=512 -> 8 K-tiles
    PJ_STAGE(d ^ 1, (kt + 1) * 64);
    PJ_COMPUTE(d);
    __syncthreads();
    d ^= 1;
  }
  PJ_COMPUTE(d);

#pragma unroll
  for (int mt = 0; mt < 4; ++mt)
#pragma unroll
    for (int nt = 0; nt < 4; ++nt)
#pragma unroll
      for (int r = 0; r < 4; ++r)
        C[(size_t)(m0 + wm + mt * 16 + quad * 4 + r) * 1024 + n0 + wn + nt * 16 + l15] =
            (half_t)acc[mt][nt][r];
}

// ---------------- flash attention with Transformer-XL relative shift --------
// R15 version verbatim (89.4us proven): R8 structure, b-major qkv[B][T][2048],
// vT[1024][B*T] addressing.
__global__ __launch_bounds__(512, 4) void k_attn(const half_t* __restrict__ qkv,
                                                 const half_t* __restrict__ rbuf,
                                                 const half_t* __restrict__ vT,
                                                 const float* __restrict__ pbu,
                                                 const float* __restrict__ pbv,
                                                 half_t* __restrict__ av) {
  __shared__ __align__(16) half_t ldsK[64][64];        // [key][dh], XOR chunks
  __shared__ __align__(16) half_t ldsV[64][64];        // [dh][key], XOR chunks
  __shared__ __align__(16) half_t ldsR[256][64];       // r ring, XOR chunks
  __shared__ __align__(16) half_t ldsP[8][16][72];     // per-wave P (wave-internal)
  const int t = threadIdx.x;
  const int wave = t >> 6, lane = t & 63, quad = lane >> 4, l15 = lane & 15;

  // work-pairing swizzle: CU-co-resident blocks get x and 7-x
  const int li = blockIdx.x + 8 * blockIdx.y;
  const int c = li & 255, kr = li >> 8;
  const int xe = kr == 0 ? (c & 7) : 7 - (c & 7);
  const int bn = (c >> 3) + (kr << 5);
  const int i0 = xe * 128;
  const int b = bn >> 4, n = bn & 15;
  const int i_base = i0 + wave * 16;
  const int p0 = 896 - i0;  // global r-row of ring origin at tile 0

  // q fragments with biases folded in
  half8 qu[2], qv[2];
#pragma unroll
  for (int ks = 0; ks < 2; ++ks) {
    const int dh0 = ks * 32 + quad * 8;
    const half8 qf = *(const half8*)&qkv[((size_t)(b * 2048 + M_LEN + i_base + l15)) * 2048 + n * 64 + dh0];
#pragma unroll
    for (int j = 0; j < 8; ++j) {
      const float qj = (float)qf[j];
      qu[ks][j] = (half_t)(qj + pbu[n * 64 + dh0 + j]);
      qv[ks][j] = (half_t)(qj + pbv[n * 64 + dh0 + j]);
    }
  }

  // E-shift lane rotation constants (loop-invariant): score col cj reads
  // window col cj + 15 - irow; rotation is uniform within a quad per r.
  int bperm_idx[4];
  bool lo_sel[4];
#pragma unroll
  for (int r = 0; r < 4; ++r) {
    const int irow = quad * 4 + r;
    bperm_idx[r] = ((lane & 48) | ((l15 + 15 - irow) & 15)) << 2;
    lo_sel[r] = (l15 <= irow);  // true: window col in tile nt; false: nt+1
  }

  f32x4 oacc[4] = {};
  float lpart[4] = {0.f, 0.f, 0.f, 0.f};
  const float k1 = 0.125f * 1.44269504088896f;  // scale * log2(e)
  const float kC = -4.0f * 1.44269504088896f;   // -C * log2(e)

  // staging geometry (K/V and steady-state R: 512 thr cover 64 rows x 8 chunks)
  const int srow = t >> 3, sc3 = t & 7;
  const int sxk = (sc3 ^ (srow & 7)) * 8;

  const int ntile = xe * 2 + 18;

  // ---- prologue: K/V tile 0, R ring rows [p0, p0+255] (4 passes) ----
  half8 kreg = *(const half8*)&qkv[((size_t)(b * 2048 + srow)) * 2048 + 1024 + n * 64 + sc3 * 8];
  half8 vreg = *(const half8*)&vT[((size_t)(n * 64 + srow)) * 8192 + b * 2048 + sc3 * 8];
  half8 rreg4[4];
  int rr4[4], rc4[4];
#pragma unroll
  for (int i = 0; i < 4; ++i) {
    const int ci = t + 512 * i;
    rr4[i] = ci >> 3; rc4[i] = ci & 7;
    const int ps = p0 + rr4[i] > 2047 ? 2047 : p0 + rr4[i];
    rreg4[i] = *(const half8*)&rbuf[(size_t)ps * 1024 + n * 64 + rc4[i] * 8];
  }
  half8 rpre;  // steady-state prefetch reg

  for (int kt = 0; kt < ntile; ++kt) {
    const int j0 = kt * 64;

    __syncthreads();  // prev-iter LDS reads done; drains vmcnt -> regs ready
    *(half8*)&ldsK[srow][sxk] = kreg;
    *(half8*)&ldsV[srow][sxk] = vreg;
    if (kt == 0) {
#pragma unroll
      for (int i = 0; i < 4; ++i) {
        const int pg = p0 + rr4[i];
        *(half8*)&ldsR[pg & 255][(rc4[i] ^ (pg & 7)) * 8] = rreg4[i];
      }
    } else {
      const int pw = j0 + p0 + 192 + srow;  // rows loaded during tile kt-1
      *(half8*)&ldsR[pw & 255][(sc3 ^ (pw & 7)) * 8] = rpre;
    }
    __syncthreads();

    // ---- prefetch tile kt+1 (regs dead after the writes above) ----
    if (kt + 1 < ntile) {
      const int j0n = j0 + 64;
      kreg = *(const half8*)&qkv[((size_t)(b * 2048 + j0n + srow)) * 2048 + 1024 + n * 64 + sc3 * 8];
      vreg = *(const half8*)&vT[((size_t)(n * 64 + srow)) * 8192 + b * 2048 + j0n + sc3 * 8];
      const int pn = j0 + p0 + 256 + srow;  // new ring rows for tile kt+1
      const int pc = pn > 2047 ? 2047 : pn;
      rpre = *(const half8*)&rbuf[(size_t)pc * 1024 + n * 64 + sc3 * 8];
    }

    // ---- AC = (q+u) @ K^T ----
    f32x4 ac[4] = {};
#pragma unroll
    for (int ks = 0; ks < 2; ++ks)
#pragma unroll
      for (int nt = 0; nt < 4; ++nt) {
        const int row = nt * 16 + l15;
        const half8 kf = *(const half8*)&ldsK[row][((ks * 4 + quad) ^ (row & 7)) * 8];
        ac[nt] = __builtin_amdgcn_mfma_f32_16x16x32_f16(qu[ks], kf, ac[nt], 0, 0, 0);
      }

    // ---- E window: E[m][c] = (q+v) . r[window c], width 80 (ring reads) ----
    const int rbg = j0 + p0 + 112 - wave * 16;  // wave's window start (global)
    f32x4 ea[5] = {};
#pragma unroll
    for (int ks = 0; ks < 2; ++ks)
#pragma unroll
      for (int et = 0; et < 5; ++et) {
        const int pr = rbg + et * 16 + l15;
        const half8 rf = *(const half8*)&ldsR[pr & 255][((ks * 4 + quad) ^ (pr & 7)) * 8];
        ea[et] = __builtin_amdgcn_mfma_f32_16x16x32_f16(qv[ks], rf, ea[et], 0, 0, 0);
      }

    // ---- scores -> p; E shift via in-register bpermute (f32) ----
    const bool maskt = j0 > i_base + 960;
#pragma unroll
    for (int r = 0; r < 4; ++r) {
      const int irow = quad * 4 + r;
      const int ig = i_base + irow;
      float rot[5];
#pragma unroll
      for (int et = 0; et < 5; ++et)
        rot[et] = __int_as_float(
            __builtin_amdgcn_ds_bpermute(bperm_idx[r], __float_as_int(ea[et][r])));
      float psum = 0.f;
#pragma unroll
      for (int nt = 0; nt < 4; ++nt) {
        const float ev = lo_sel[r] ? rot[nt] : rot[nt + 1];
        const int cj = nt * 16 + l15;
        float p = __builtin_amdgcn_exp2f(fmaf(ac[nt][r] + ev, k1, kC));
        if (maskt && (j0 + cj > ig + M_LEN)) p = 0.f;
        psum += p;
        ldsP[wave][irow][cj] = (half_t)p;
      }
      lpart[r] += psum;
    }
    __builtin_amdgcn_wave_barrier();  // P round trip is wave-internal

    // ---- PV ----
    half8 pa[2];
#pragma unroll
    for (int ks = 0; ks < 2; ++ks)
      pa[ks] = *(const half8*)&ldsP[wave][l15][ks * 32 + quad * 8];
#pragma unroll
    for (int ks = 0; ks < 2; ++ks)
#pragma unroll
      for (int dnt = 0; dnt < 4; ++dnt) {
        const int row = dnt * 16 + l15;
        const half8 vf = *(const half8*)&ldsV[row][((ks * 4 + quad) ^ (row & 7)) * 8];
        oacc[dnt] = __builtin_amdgcn_mfma_f32_16x16x32_f16(pa[ks], vf, oacc[dnt], 0, 0, 0);
      }
  }

  // final l-sum reduction + normalize + store
#pragma unroll
  for (int r = 0; r < 4; ++r) {
    float l = lpart[r];
#pragma unroll
    for (int off = 1; off < 16; off <<= 1) l += __shfl_xor(l, off);
    const float inv = 1.0f / l;
    const int ig = i_base + quad * 4 + r;
#pragma unroll
    for (int dnt = 0; dnt < 4; ++dnt)
      av[((size_t)ig * BATCH + b) * 1024 + n * 64 + dnt * 16 + l15] = (half_t)(oacc[dnt][r] * inv);
  }
}

// -------- residual + LayerNorm (one block per row; sums 2 fp16 partials) ----
__global__ __launch_bounds__(256) void k_ln(const float* __restrict__ x,
                                            const half_t* __restrict__ ao0,
                                            const half_t* __restrict__ ao1,
                                            const float* __restrict__ gamma,
                                            const float* __restrict__ beta,
                                            float* __restrict__ out) {
  const int row = blockIdx.x;
  const int t = threadIdx.x;
  const float4 xv = ((const float4*)(x + (size_t)row * 1024))[t];
  const half4v a4 = ((const half4v*)(ao0 + (size_t)row * 1024))[t];
  const half4v b4 = ((const half4v*)(ao1 + (size_t)row * 1024))[t];
  const float y0 = xv.x + (float)a4[0] + (float)b4[0];
  const float y1 = xv.y + (float)a4[1] + (float)b4[1];
  const float y2 = xv.z + (float)a4[2] + (float)b4[2];
  const float y3 = xv.w + (float)a4[3] + (float)b4[3];
  float s = y0 + y1 + y2 + y3;
  float ss = y0 * y0 + y1 * y1 + y2 * y2 + y3 * y3;
#pragma unroll
  for (int off = 1; off < 64; off <<= 1) {
    s += __shfl_xor(s, off);
    ss += __shfl_xor(ss, off);
  }
  __shared__ float sb[4], ssb[4];
  if ((t & 63) == 0) { sb[t >> 6] = s; ssb[t >> 6] = ss; }
  __syncthreads();
  s = sb[0] + sb[1] + sb[2] + sb[3];
  ss = ssb[0] + ssb[1] + ssb[2] + ssb[3];
  const float mean = s * (1.f / 1024.f);
  const float var = ss * (1.f / 1024.f) - mean * mean;
  const float rstd = rsqrtf(var + 1e-5f);
  const float4 g = ((const float4*)gamma)[t];
  const float4 be = ((const float4*)beta)[t];
  float4 o;
  o.x = (y0 - mean) * rstd * g.x + be.x;
  o.y = (y1 - mean) * rstd * g.y + be.y;
  o.z = (y2 - mean) * rstd * g.z + be.z;
  o.w = (y3 - mean) * rstd * g.w + be.w;
  ((float4*)(out + (size_t)row * 1024))[t] = o;
}

// ---------------------------------------------------------------------------
extern "C" void kernel_launch(void* const* d_in, const int* in_sizes, int n_in,
                              void* d_out, int out_size, void* d_ws, size_t ws_size,
                              hipStream_t stream) {
  const float* x     = (const float*)d_in[0];
  const float* pos   = (const float*)d_in[1];
  const float* pbu   = (const float*)d_in[2];
  const float* pbv   = (const float*)d_in[3];
  const float* mem   = (const float*)d_in[4];
  const float* Wqkv  = (const float*)d_in[5];
  const float* Wrel  = (const float*)d_in[6];
  const float* Wo    = (const float*)d_in[7];
  const float* gamma = (const float*)d_in[8];
  const float* beta  = (const float*)d_in[9];
  float* out = (float*)d_out;

  half_t* ws    = (half_t*)d_ws;
  half_t* cbf   = ws;                 // [4][2048][1024] b-major
  half_t* posb  = cbf + 8388608;      // [2048][1024]
  half_t* wqkvT = posb + 2097152;     // [3072][1024]
  half_t* wrelT = wqkvT + 3145728;    // [1024][1024]
  half_t* woT   = wrelT + 1048576;    // [1024][1024]
  half_t* qkv   = woT + 1048576;      // [4][2048][2048] b-major (Q|K)
  half_t* rb    = qkv + 16777216;     // [2048][1024]
  half_t* vT    = rb + 2097152;       // [1024][4*2048]
  half_t* av    = vT + 8388608;       // [4096][1024]
  half_t* aout0 = qkv;                // reuse qkv region (partial 0)
  half_t* aout1 = qkv + 4194304;      // partial 1

  k_pre<<<11520, 256, 0, stream>>>(mem, x, pos, Wqkv, Wrel, Wo, cbf, posb, wqkvT, wrelT, woT);
  k_gemm_qkv_pos<<<352, 512, 0, stream>>>(cbf, wqkvT, qkv, posb, wrelT, rb, vT);
  k_attn<<<dim3(8, 64), 512, 0, stream>>>(qkv, rb, vT, pbu, pbv, av);
  k_gemm_proj<<<256, 512, 0, stream>>>(av, woT, aout0, aout1);
  k_ln<<<4096, 256, 0, stream>>>(x, aout0, aout1, gamma, beta, out);
}

// Round 12
// 306.345 us; speedup vs baseline: 1.0154x; 1.0154x over previous
//
#include <hip/hip_runtime.h>
#include <math.h>
#include <cstdint>
#include <cstddef>

// ---------------------------------------------------------------------------
// Transformer-XL relative multihead attention, MI355X (gfx950)
// S=1024, M=1024, T=2048, B=4, D=1024, H=16, DH=64
// R20: k_attn single-barrier-per-tile. K/V double-buffered (+16KB); per tile:
//      prefetch(kt+1)->regs, compute from buf[kt&1]+ring, write regs ->
//      buf[(kt+1)&1] + ring rows [j0+p0+192,+256) (slots == [j0+p0-64,j0+p0),
//      outside window kt, last read kt-1), ONE barrier. ldsP 72->64 stride
//      with chunk-XOR swizzle (write c^=irow&7, read c^=l15&7) to fit LDS =
//      16K+16K+32K+16K = 81920 B exactly = half CU -> 2 blocks/CU preserved.
//      Ring row coverage/clamp set identical to R8 -> bitwise-same output.
//      All other kernels unchanged from R19 (311us; qkv closed: round-
//      quantized at 2 rounds regardless of structure, R13/15/18/19 equal).
// ---------------------------------------------------------------------------

typedef _Float16 half_t;
typedef _Float16 half8 __attribute__((ext_vector_type(8)));
typedef _Float16 half4v __attribute__((ext_vector_type(4)));
typedef float f32x4 __attribute__((ext_vector_type(4)));

#define S_LEN 1024
#define M_LEN 1024
#define T_LEN 2048
#define BATCH 4
#define NHEAD 16

__device__ inline void async_copy16(const half_t* g, half_t* l) {
  __builtin_amdgcn_global_load_lds(
      (const __attribute__((address_space(1))) void*)g,
      (__attribute__((address_space(3))) void*)l, 16, 0, 0);
}

// ---- fused pre-pass: convert (b-major cbf | posb) + weight transposes -----
__global__ __launch_bounds__(256) void k_pre(const float* __restrict__ mem,
                                             const float* __restrict__ x,
                                             const float* __restrict__ pos,
                                             const float* __restrict__ Wqkv,
                                             const float* __restrict__ Wrel,
                                             const float* __restrict__ Wo,
                                             half_t* __restrict__ cbf,
                                             half_t* __restrict__ posb,
                                             half_t* __restrict__ wqkvT,
                                             half_t* __restrict__ wrelT,
                                             half_t* __restrict__ woT) {
  __shared__ float tile[64][65];
  const int bid = blockIdx.x;
  const int t = threadIdx.x;
  if (bid < 10240) {
    const int i = bid * 256 + t;  // 2621440 float4s total
    if (i < 2097152) {            // mem (sel=0) | x (sel=1), b-major dest
      const int off = i & 1048575;
      const int sel = i >> 20;
      const float4 v = ((const float4*)(sel ? x : mem))[off];
      const int row = off >> 8, d4 = off & 255;        // src row = t*4+b
      const int drow = (row & 3) * 2048 + sel * 1024 + (row >> 2);
      half4v h;
      h[0] = (half_t)v.x; h[1] = (half_t)v.y; h[2] = (half_t)v.z; h[3] = (half_t)v.w;
      ((half4v*)cbf)[(drow << 8) + d4] = h;
    } else {                      // pos, linear
      const int off = i - 2097152;
      const float4 v = ((const float4*)pos)[off];
      half4v h;
      h[0] = (half_t)v.x; h[1] = (half_t)v.y; h[2] = (half_t)v.z; h[3] = (half_t)v.w;
      ((half4v*)posb)[off] = h;
    }
    return;
  }
  const int tb = bid - 10240;
  const int bx = tb & 15, y = tb >> 4;
  const float* src; half_t* dst; int C, c0;
  if (y < 48)      { src = Wqkv; dst = wqkvT; C = 3072; c0 = y * 64; }
  else if (y < 64) { src = Wrel; dst = wrelT; C = 1024; c0 = (y - 48) * 64; }
  else             { src = Wo;   dst = woT;   C = 1024; c0 = (y - 64) * 64; }
  const int r0 = bx * 64;
  const int tx = t & 63, ty4 = t >> 6;
#pragma unroll
  for (int k = 0; k < 16; ++k) {
    int row = k * 4 + ty4;
    tile[row][tx] = src[(size_t)(r0 + row) * C + c0 + tx];
  }
  __syncthreads();
#pragma unroll
  for (int k = 0; k < 16; ++k) {
    int orow = k * 4 + ty4;
    dst[(size_t)(c0 + orow) * 1024 + r0 + tx] = (half_t)tile[tx][orow];
  }
}

// ---------- 256^2-tile 8-phase counted-vmcnt GEMM: k | q(live) | vT | pos ---
#define QK_STA(tile_, h_)                                                      \
  do {                                                                         \
    _Pragma("unroll") for (int i_ = 0; i_ < 2; ++i_) {                         \
      const int r_ = (t >> 3) + i_ * 64;                                       \
      async_copy16(&A[(size_t)(m0 + (h_) * 128 + r_) * 1024 +                  \
                      (tile_) * 64 + scl],                                     \
                   &sA[(tile_) & 1][h_][r_][(t & 7) * 8]);                     \
    }                                                                          \
  } while (0)

#define QK_STB(tile_, h_)                                                      \
  do {                                                                         \
    _Pragma("unroll") for (int i_ = 0; i_ < 2; ++i_) {                         \
      const int r_ = (t >> 3) + i_ * 64;                                       \
      async_copy16(&B[(size_t)(n0 + (h_) * 128 + r_) * 1024 +                  \
                      (tile_) * 64 + scl],                                     \
                   &sB[(tile_) & 1][h_][r_][(t & 7) * 8]);                     \
    }                                                                          \
  } while (0)

#define QK_LDA(d_, mq_)                                                        \
  do {                                                                         \
    _Pragma("unroll") for (int mt_ = 0; mt_ < 4; ++mt_)                        \
      _Pragma("unroll") for (int ks_ = 0; ks_ < 2; ++ks_) {                    \
        const int lr_ = ((mq_) * 4 + mt_) * 16 + l15;                          \
        af[mt_][ks_] = *(const half8*)&sA[d_][wha][lr_]                        \
                           [((ks_ * 4 + quad) ^ (lr_ & 7)) * 8];               \
      }                                                                        \
  } while (0)

#define QK_LDB(d_, nh_)                                                        \
  do {                                                                         \
    _Pragma("unroll") for (int ntl_ = 0; ntl_ < 2; ++ntl_)                     \
      _Pragma("unroll") for (int ks_ = 0; ks_ < 2; ++ks_) {                    \
        const int lr_ = wnl + ((nh_) * 2 + ntl_) * 16 + l15;                   \
        bf[nh_][ntl_][ks_] = *(const half8*)&sB[d_][whb][lr_]                  \
                                 [((ks_ * 4 + quad) ^ (lr_ & 7)) * 8];         \
      }                                                                        \
  } while (0)

#define QK_MMA(mq_, nh_)                                                       \
  do {                                                                         \
    __builtin_amdgcn_s_setprio(1);                                             \
    _Pragma("unroll") for (int mt_ = 0; mt_ < 4; ++mt_)                        \
      _Pragma("unroll") for (int ntl_ = 0; ntl_ < 2; ++ntl_)                   \
        _Pragma("unroll") for (int ks_ = 0; ks_ < 2; ++ks_)                    \
          acc[(mq_) * 4 + mt_][(nh_) * 2 + ntl_] =                             \
              __builtin_amdgcn_mfma_f32_16x16x32_f16(                          \
                  af[mt_][ks_], bf[nh_][ntl_][ks_],                            \
                  acc[(mq_) * 4 + mt_][(nh_) * 2 + ntl_], 0, 0, 0);            \
    __builtin_amdgcn_s_setprio(0);                                             \
  } while (0)

__global__ __launch_bounds__(512, 2) void k_gemm_qkv_pos(const half_t* __restrict__ cbf,
                                                         const half_t* __restrict__ wqkvT,
                                                         half_t* __restrict__ qkv,
                                                         const half_t* __restrict__ posb,
                                                         const half_t* __restrict__ wrelT,
                                                         half_t* __restrict__ rb,
                                                         half_t* __restrict__ vT) {
  __shared__ half_t sA[2][2][128][64];   // 64 KB
  __shared__ half_t sB[2][2][128][64];   // 64 KB
  const int t = threadIdx.x;
  const int wave = t >> 6, lane = t & 63, quad = lane >> 4, l15 = lane & 15;
  // bijective XCD swizzle (352 % 8 == 0): each XCD gets a contiguous chunk
  const int bid0 = blockIdx.x;
  const int bid = (bid0 & 7) * 44 + (bid0 >> 3);
  const half_t* A; const half_t* B; half_t* C; int m0, n0, N;
  if (bid < 128) {        // K: cbf[8192] @ Wk^T -> qkv cols [1024,2048)
    A = cbf;  B = wqkvT; C = qkv; N = 2048;
    m0 = (bid & 31) * 256; n0 = 1024 + (bid >> 5) * 256;
  } else if (bid < 192) { // Q: only rows t>=1024 per batch (attn-live)
    const int q = bid - 128;
    const int ml = q & 15;          // batch = ml>>2, local t-tile = ml&3
    A = cbf;  B = wqkvT; C = qkv; N = 2048;
    m0 = (ml >> 2) * 2048 + 1024 + (ml & 3) * 256;
    n0 = (q >> 4) * 256;
  } else if (bid < 320) { // V^T: Wv^T[1024] @ cbf^T -> vT[1024][8192]
    const int b2 = bid - 192;
    A = wqkvT + 2048 * 1024; B = cbf; C = vT; N = 8192;
    m0 = (b2 & 3) * 256; n0 = (b2 >> 2) * 256;
  } else {                // pos: posb[2048] @ Wrel^T -> rb[2048][1024]
    const int b2 = bid - 320;
    A = posb; B = wrelT; C = rb; N = 1024;
    m0 = (b2 & 7) * 256; n0 = (b2 >> 3) * 256;
  }
  const int scl = ((t & 7) ^ ((t >> 3) & 7)) * 8;
  const int wm = (wave >> 2) * 128, wn = (wave & 3) * 64;
  const int wha = wave >> 2;            // wave's static A-half
  const int whb = (wave & 3) >> 1;      // wave's static B-half
  const int wnl = (wave & 1) * 64;      // local B row base within half

  f32x4 acc[8][4] = {};
  half8 af[4][2], bf[2][2][2];

  // prologue: tile 0 fully + (1).A0 -> exactly 1 half-tile in flight at gate
  QK_STA(0, 0); QK_STA(0, 1); QK_STB(0, 0); QK_STB(0, 1); QK_STA(1, 0);

  for (int kt = 0; kt < 16; ++kt) {
    const int d = kt & 1;
    asm volatile("s_waitcnt vmcnt(2)" ::: "memory");   // counted gate, not 0
    __builtin_amdgcn_s_barrier();
    // ph1: quadrant (m0..3, n0..1)
    QK_LDA(d, 0); QK_LDB(d, 0); QK_STA(kt + 1, 1);
    __builtin_amdgcn_s_barrier();
    QK_MMA(0, 0);
    __builtin_amdgcn_s_barrier();
    // ph2: quadrant (m0..3, n2..3)
    QK_LDB(d, 1); QK_STB(kt + 1, 0);
    __builtin_amdgcn_s_barrier();
    QK_MMA(0, 1);
    __builtin_amdgcn_s_barrier();
    // ph3: quadrant (m4..7, n0..1)
    QK_LDA(d, 1); QK_STB(kt + 1, 1);
    __builtin_amdgcn_s_barrier();
    QK_MMA(1, 0);
    __builtin_amdgcn_s_barrier();
    // ph4: quadrant (m4..7, n2..3)
    QK_STA(kt + 2, 0);
    __builtin_amdgcn_s_barrier();
    QK_MMA(1, 1);
    // next iteration's gate barrier closes this tile
  }

#pragma unroll
  for (int mt = 0; mt < 8; ++mt)
#pragma unroll
    for (int nt = 0; nt < 4; ++nt)
#pragma unroll
      for (int r = 0; r < 4; ++r)
        C[(size_t)(m0 + wm + mt * 16 + quad * 4 + r) * N + n0 + wn + nt * 16 + l15] =
            (half_t)acc[mt][nt][r];
}

// ------- proj GEMM: 128x256 tiles, 8-wave dbuf 2-phase, split-K=2 ----------
#define PJ_STAGE(buf_, k0_)                                                    \
  do {                                                                         \
    _Pragma("unroll") for (int i_ = 0; i_ < 2; ++i_) {                         \
      const int r0_ = wave * 16 + i_ * 8;                                      \
      async_copy16(&A[(size_t)(m0 + r0_ + srw) * 1024 + (k0_) + scl],          \
                   &pA[buf_][r0_][0]);                                         \
    }                                                                          \
    _Pragma("unroll") for (int i_ = 0; i_ < 4; ++i_) {                         \
      const int r0_ = wave * 32 + i_ * 8;                                      \
      async_copy16(&B[(size_t)(n0 + r0_ + srw) * 1024 + (k0_) + scl],          \
                   &pB[buf_][r0_][0]);                                         \
    }                                                                          \
  } while (0)

#define PJ_COMPUTE(d_)                                                         \
  do {                                                                         \
    _Pragma("unroll") for (int ks_ = 0; ks_ < 2; ++ks_) {                      \
      half8 bf_[4];                                                            \
      _Pragma("unroll") for (int nt_ = 0; nt_ < 4; ++nt_) {                    \
        const int rw_ = wn + nt_ * 16 + l15;                                   \
        bf_[nt_] =                                                             \
            *(const half8*)&pB[d_][rw_][((ks_ * 4 + quad) ^ (rw_ & 7)) * 8];   \
      }                                                                        \
      half8 af_[4];                                                            \
      _Pragma("unroll") for (int mt_ = 0; mt_ < 4; ++mt_) {                    \
        const int rw_ = wm + mt_ * 16 + l15;                                   \
        af_[mt_] =                                                             \
            *(const half8*)&pA[d_][rw_][((ks_ * 4 + quad) ^ (rw_ & 7)) * 8];   \
      }                                                                        \
      __builtin_amdgcn_s_setprio(1);                                           \
      _Pragma("unroll") for (int mt_ = 0; mt_ < 4; ++mt_)                      \
        _Pragma("unroll") for (int nt_ = 0; nt_ < 4; ++nt_)                    \
          acc[mt_][nt_] = __builtin_amdgcn_mfma_f32_16x16x32_f16(              \
              af_[mt_], bf_[nt_], acc[mt_][nt_], 0, 0, 0);                     \
      __builtin_amdgcn_s_setprio(0);                                           \
    }                                                                          \
  } while (0)

__global__ __launch_bounds__(512, 2) void k_gemm_proj(const half_t* __restrict__ av,
                                                      const half_t* __restrict__ woT,
                                                      half_t* __restrict__ out0,
                                                      half_t* __restrict__ out1) {
  __shared__ half_t pA[2][128][64];     // 32 KB
  __shared__ half_t pB[2][256][64];     // 64 KB
  const int t = threadIdx.x;
  const int wave = t >> 6, lane = t & 63, quad = lane >> 4, l15 = lane & 15;
  const int bid0 = blockIdx.x;
  const int bs = (bid0 & 7) * 32 + (bid0 >> 3);
  const int h = bs >> 7, b2 = bs & 127;
  const int m0 = (b2 & 31) * 128, n0 = (b2 >> 5) * 256;
  const half_t* A = av + h * 512;
  const half_t* B = woT + h * 512;
  half_t* C = h ? out1 : out0;
  const int srw = lane >> 3;
  const int scl = ((lane & 7) ^ srw) * 8;
  const int wm = (wave >> 2) * 64, wn = (wave & 3) * 64;

  f32x4 acc[4][4] = {};

  PJ_STAGE(0, 0);
  __syncthreads();
  int d = 0;
  for (int kt = 0; kt < 7; ++kt) {      // K=512 -> 8 K-tiles
    PJ_STAGE(d ^ 1, (kt + 1) * 64);
    PJ_COMPUTE(d);
    __syncthreads();
    d ^= 1;
  }
  PJ_COMPUTE(d);

#pragma unroll
  for (int mt = 0; mt < 4; ++mt)
#pragma unroll
    for (int nt = 0; nt < 4; ++nt)
#pragma unroll
      for (int r = 0; r < 4; ++r)
        C[(size_t)(m0 + wm + mt * 16 + quad * 4 + r) * 1024 + n0 + wn + nt * 16 + l15] =
            (half_t)acc[mt][nt][r];
}

// ---------------- flash attention with Transformer-XL relative shift --------
// R20: single barrier per tile. K/V double-buffered; per tile kt:
//   prefetch(kt+1)->regs; compute from ldsK/V[kt&1]+ring; write regs ->
//   ldsK/V[(kt+1)&1] + ring rows [j0+p0+192,+256); ONE __syncthreads.
// ldsP stride 64 with chunk-XOR swizzle (write chunk c^(irow&7), read
// chunk (ks*4+quad)^(l15&7)). LDS total 81920 B = exactly half CU.
__global__ __launch_bounds__(512, 4) void k_attn(const half_t* __restrict__ qkv,
                                                 const half_t* __restrict__ rbuf,
                                                 const half_t* __restrict__ vT,
                                                 const float* __restrict__ pbu,
                                                 const float* __restrict__ pbv,
                                                 half_t* __restrict__ av) {
  __shared__ __align__(16) half_t ldsK[2][64][64];     // [dbuf][key][dh], XOR
  __shared__ __align__(16) half_t ldsV[2][64][64];     // [dbuf][dh][key], XOR
  __shared__ __align__(16) half_t ldsR[256][64];       // r ring, XOR chunks
  __shared__ __align__(16) half_t ldsP[8][16][64];     // per-wave P, XOR chunks
  const int t = threadIdx.x;
  const int wave = t >> 6, lane = t & 63, quad = lane >> 4, l15 = lane & 15;

  // work-pairing swizzle: CU-co-resident blocks get x and 7-x
  const int li = blockIdx.x + 8 * blockIdx.y;
  const int c = li & 255, kr = li >> 8;
  const int xe = kr == 0 ? (c & 7) : 7 - (c & 7);
  const int bn = (c >> 3) + (kr << 5);
  const int i0 = xe * 128;
  const int b = bn >> 4, n = bn & 15;
  const int i_base = i0 + wave * 16;
  const int p0 = 896 - i0;  // global r-row of ring origin at tile 0

  // q fragments with biases folded in
  half8 qu[2], qv[2];
#pragma unroll
  for (int ks = 0; ks < 2; ++ks) {
    const int dh0 = ks * 32 + quad * 8;
    const half8 qf = *(const half8*)&qkv[((size_t)(b * 2048 + M_LEN + i_base + l15)) * 2048 + n * 64 + dh0];
#pragma unroll
    for (int j = 0; j < 8; ++j) {
      const float qj = (float)qf[j];
      qu[ks][j] = (half_t)(qj + pbu[n * 64 + dh0 + j]);
      qv[ks][j] = (half_t)(qj + pbv[n * 64 + dh0 + j]);
    }
  }

  // E-shift lane rotation constants (loop-invariant)
  int bperm_idx[4];
  bool lo_sel[4];
#pragma unroll
  for (int r = 0; r < 4; ++r) {
    const int irow = quad * 4 + r;
    bperm_idx[r] = ((lane & 48) | ((l15 + 15 - irow) & 15)) << 2;
    lo_sel[r] = (l15 <= irow);  // true: window col in tile nt; false: nt+1
  }

  f32x4 oacc[4] = {};
  float lpart[4] = {0.f, 0.f, 0.f, 0.f};
  const float k1 = 0.125f * 1.44269504088896f;  // scale * log2(e)
  const float kC = -4.0f * 1.44269504088896f;   // -C * log2(e)

  // staging geometry (512 thr cover 64 rows x 8 chunks)
  const int srow = t >> 3, sc3 = t & 7;
  const int sxk = (sc3 ^ (srow & 7)) * 8;

  const int ntile = xe * 2 + 18;

  // ---- prologue: K/V tile 0 -> buf 0; ring rows [p0, p0+255] (4 passes) ----
  {
    const half8 k0 = *(const half8*)&qkv[((size_t)(b * 2048 + srow)) * 2048 + 1024 + n * 64 + sc3 * 8];
    const half8 v0 = *(const half8*)&vT[((size_t)(n * 64 + srow)) * 8192 + b * 2048 + sc3 * 8];
    *(half8*)&ldsK[0][srow][sxk] = k0;
    *(half8*)&ldsV[0][srow][sxk] = v0;
#pragma unroll
    for (int i = 0; i < 4; ++i) {
      const int ci = t + 512 * i;
      const int rr = ci >> 3, rc = ci & 7;
      const int pg = p0 + rr;
      const int ps = pg > 2047 ? 2047 : pg;
      const half8 rv = *(const half8*)&rbuf[(size_t)ps * 1024 + n * 64 + rc * 8];
      *(half8*)&ldsR[pg & 255][(rc ^ (pg & 7)) * 8] = rv;
    }
  }
  __syncthreads();

  half8 kreg, vreg, rpre;

  for (int kt = 0; kt < ntile; ++kt) {
    const int j0 = kt * 64;
    const int d = kt & 1;

    // ---- prefetch tile kt+1 (consumed by the writes at tile end) ----
    if (kt + 1 < ntile) {
      const int j0n = j0 + 64;
      kreg = *(const half8*)&qkv[((size_t)(b * 2048 + j0n + srow)) * 2048 + 1024 + n * 64 + sc3 * 8];
      vreg = *(const half8*)&vT[((size_t)(n * 64 + srow)) * 8192 + b * 2048 + j0n + sc3 * 8];
      const int pn = j0 + p0 + 192 + srow;  // new ring rows for window kt+1
      const int pc = pn > 2047 ? 2047 : pn;
      rpre = *(const half8*)&rbuf[(size_t)pc * 1024 + n * 64 + sc3 * 8];
    }

    // ---- AC = (q+u) @ K^T ----
    f32x4 ac[4] = {};
#pragma unroll
    for (int ks = 0; ks < 2; ++ks)
#pragma unroll
      for (int nt = 0; nt < 4; ++nt) {
        const int row = nt * 16 + l15;
        const half8 kf = *(const half8*)&ldsK[d][row][((ks * 4 + quad) ^ (row & 7)) * 8];
        ac[nt] = __builtin_amdgcn_mfma_f32_16x16x32_f16(qu[ks], kf, ac[nt], 0, 0, 0);
      }

    // ---- E window: E[m][c] = (q+v) . r[window c], width 80 (ring reads) ----
    const int rbg = j0 + p0 + 112 - wave * 16;  // wave's window start (global)
    f32x4 ea[5] = {};
#pragma unroll
    for (int ks = 0; ks < 2; ++ks)
#pragma unroll
      for (int et = 0; et < 5; ++et) {
        const int pr = rbg + et * 16 + l15;
        const half8 rf = *(const half8*)&ldsR[pr & 255][((ks * 4 + quad) ^ (pr & 7)) * 8];
        ea[et] = __builtin_amdgcn_mfma_f32_16x16x32_f16(qv[ks], rf, ea[et], 0, 0, 0);
      }

    // ---- scores -> p; E shift via in-register bpermute (f32) ----
    const bool maskt = j0 > i_base + 960;
#pragma unroll
    for (int r = 0; r < 4; ++r) {
      const int irow = quad * 4 + r;
      const int ig = i_base + irow;
      float rot[5];
#pragma unroll
      for (int et = 0; et < 5; ++et)
        rot[et] = __int_as_float(
            __builtin_amdgcn_ds_bpermute(bperm_idx[r], __float_as_int(ea[et][r])));
      float psum = 0.f;
#pragma unroll
      for (int nt = 0; nt < 4; ++nt) {
        const float ev = lo_sel[r] ? rot[nt] : rot[nt + 1];
        const int cj = nt * 16 + l15;
        float p = __builtin_amdgcn_exp2f(fmaf(ac[nt][r] + ev, k1, kC));
        if (maskt && (j0 + cj > ig + M_LEN)) p = 0.f;
        psum += p;
        // P chunk-XOR: logical chunk c = nt*2 + (l15>>3), stored at c^(irow&7)
        ldsP[wave][irow][(((nt * 2 + (l15 >> 3)) ^ (irow & 7)) << 3) + (l15 & 7)] = (half_t)p;
      }
      lpart[r] += psum;
    }
    __builtin_amdgcn_wave_barrier();  // P round trip is wave-internal

    // ---- PV ----
    half8 pa[2];
#pragma unroll
    for (int ks = 0; ks < 2; ++ks)
      pa[ks] = *(const half8*)&ldsP[wave][l15][((ks * 4 + quad) ^ (l15 & 7)) * 8];
#pragma unroll
    for (int ks = 0; ks < 2; ++ks)
#pragma unroll
      for (int dnt = 0; dnt < 4; ++dnt) {
        const int row = dnt * 16 + l15;
        const half8 vf = *(const half8*)&ldsV[d][row][((ks * 4 + quad) ^ (row & 7)) * 8];
        oacc[dnt] = __builtin_amdgcn_mfma_f32_16x16x32_f16(pa[ks], vf, oacc[dnt], 0, 0, 0);
      }

    // ---- write prefetched tile kt+1: buf d^1 + ring (slots dead since kt-1) ----
    if (kt + 1 < ntile) {
      *(half8*)&ldsK[d ^ 1][srow][sxk] = kreg;
      *(half8*)&ldsV[d ^ 1][srow][sxk] = vreg;
      const int pw = j0 + p0 + 192 + srow;
      *(half8*)&ldsR[pw & 255][(sc3 ^ (pw & 7)) * 8] = rpre;
    }
    __syncthreads();  // the ONLY barrier: separates kt writes from kt+1 reads
  }

  // final l-sum reduction + normalize + store
#pragma unroll
  for (int r = 0; r < 4; ++r) {
    float l = lpart[r];
#pragma unroll
    for (int off = 1; off < 16; off <<= 1) l += __shfl_xor(l, off);
    const float inv = 1.0f / l;
    const int ig = i_base + quad * 4 + r;
#pragma unroll
    for (int dnt = 0; dnt < 4; ++dnt)
      av[((size_t)ig * BATCH + b) * 1024 + n * 64 + dnt * 16 + l15] = (half_t)(oacc[dnt][r] * inv);
  }
}

// -------- residual + LayerNorm (one block per row; sums 2 fp16 partials) ----
__global__ __launch_bounds__(256) void k_ln(const float* __restrict__ x,
                                            const half_t* __restrict__ ao0,
                                            const half_t* __restrict__ ao1,
                                            const float* __restrict__ gamma,
                                            const float* __restrict__ beta,
                                            float* __restrict__ out) {
  const int row = blockIdx.x;
  const int t = threadIdx.x;
  const float4 xv = ((const float4*)(x + (size_t)row * 1024))[t];
  const half4v a4 = ((const half4v*)(ao0 + (size_t)row * 1024))[t];
  const half4v b4 = ((const half4v*)(ao1 + (size_t)row * 1024))[t];
  const float y0 = xv.x + (float)a4[0] + (float)b4[0];
  const float y1 = xv.y + (float)a4[1] + (float)b4[1];
  const float y2 = xv.z + (float)a4[2] + (float)b4[2];
  const float y3 = xv.w + (float)a4[3] + (float)b4[3];
  float s = y0 + y1 + y2 + y3;
  float ss = y0 * y0 + y1 * y1 + y2 * y2 + y3 * y3;
#pragma unroll
  for (int off = 1; off < 64; off <<= 1) {
    s += __shfl_xor(s, off);
    ss += __shfl_xor(ss, off);
  }
  __shared__ float sb[4], ssb[4];
  if ((t & 63) == 0) { sb[t >> 6] = s; ssb[t >> 6] = ss; }
  __syncthreads();
  s = sb[0] + sb[1] + sb[2] + sb[3];
  ss = ssb[0] + ssb[1] + ssb[2] + ssb[3];
  const float mean = s * (1.f / 1024.f);
  const float var = ss * (1.f / 1024.f) - mean * mean;
  const float rstd = rsqrtf(var + 1e-5f);
  const float4 g = ((const float4*)gamma)[t];
  const float4 be = ((const float4*)beta)[t];
  float4 o;
  o.x = (y0 - mean) * rstd * g.x + be.x;
  o.y = (y1 - mean) * rstd * g.y + be.y;
  o.z = (y2 - mean) * rstd * g.z + be.z;
  o.w = (y3 - mean) * rstd * g.w + be.w;
  ((float4*)(out + (size_t)row * 1024))[t] = o;
}

// ---------------------------------------------------------------------------
extern "C" void kernel_launch(void* const* d_in, const int* in_sizes, int n_in,
                              void* d_out, int out_size, void* d_ws, size_t ws_size,
                              hipStream_t stream) {
  const float* x     = (const float*)d_in[0];
  const float* pos   = (const float*)d_in[1];
  const float* pbu   = (const float*)d_in[2];
  const float* pbv   = (const float*)d_in[3];
  const float* mem   = (const float*)d_in[4];
  const float* Wqkv  = (const float*)d_in[5];
  const float* Wrel  = (const float*)d_in[6];
  const float* Wo    = (const float*)d_in[7];
  const float* gamma = (const float*)d_in[8];
  const float* beta  = (const float*)d_in[9];
  float* out = (float*)d_out;

  half_t* ws    = (half_t*)d_ws;
  half_t* cbf   = ws;                 // [4][2048][1024] b-major
  half_t* posb  = cbf + 8388608;      // [2048][1024]
  half_t* wqkvT = posb + 2097152;     // [3072][1024]
  half_t* wrelT = wqkvT + 3145728;    // [1024][1024]
  half_t* woT   = wrelT + 1048576;    // [1024][1024]
  half_t* qkv   = woT + 1048576;      // [4][2048][2048] b-major (Q|K)
  half_t* rb    = qkv + 16777216;     // [2048][1024]
  half_t* vT    = rb + 2097152;       // [1024][4*2048]
  half_t* av    = vT + 8388608;       // [4096][1024]
  half_t* aout0 = qkv;                // reuse qkv region (partial 0)
  half_t* aout1 = qkv + 4194304;      // partial 1

  k_pre<<<11520, 256, 0, stream>>>(mem, x, pos, Wqkv, Wrel, Wo, cbf, posb, wqkvT, wrelT, woT);
  k_gemm_qkv_pos<<<352, 512, 0, stream>>>(cbf, wqkvT, qkv, posb, wrelT, rb, vT);
  k_attn<<<dim3(8, 64), 512, 0, stream>>>(qkv, rb, vT, pbu, pbv, av);
  k_gemm_proj<<<256, 512, 0, stream>>>(av, woT, aout0, aout1);
  k_ln<<<4096, 256, 0, stream>>>(x, aout0, aout1, gamma, beta, out);
}